// Round 1
// baseline (40659.229 us; speedup 1.0000x reference)
//
#include <hip/hip_runtime.h>
#include <hip/hip_bf16.h>
#include <math.h>

// ---------------------------------------------------------------------------
// KashfModel forward on MI355X. Round 0: correctness-first, all-fp32 vector.
// B=2 T=1024 D=1024 E=512 H=16 HD=64 EXP=1024 DFF=1365 L=6 V=50257
// ---------------------------------------------------------------------------

namespace {

constexpr int kB = 2, kT = 1024, kV = 50257, kD = 1024, kE = 512;
constexpr int kH = 16, kHD = 64, kEXP = 1024, kDFF = 1365, kL = 6;
constexpr int kN = kB * kT; // 2048 tokens
constexpr float kCAP = 50.0f;
constexpr float kEPS = 1e-6f;

// ---------------- rope tables: cos/sin[t][i], i<32, theta=500000 ------------
__global__ __launch_bounds__(256) void rope_tables_k(float* __restrict__ cost,
                                                     float* __restrict__ sint) {
  int idx = blockIdx.x * 256 + threadIdx.x; // kT*32 = 32768
  int t = idx >> 5, i = idx & 31;
  float inv = __powf(500000.0f, -(float)i / 32.0f);
  float ang = (float)t * inv;
  cost[idx] = cosf(ang);
  sint[idx] = sinf(ang);
}

// ---------------- generic fp32 GEMM: C[2048 x M] = A[2048 x K] @ B[K x M] ---
// 128x128 tile, BK=8, 256 threads, 8x8 microtile. EMBED: A row gathered via tok.
template <bool ACCUM, bool EMBED>
__global__ __launch_bounds__(256) void gemm128_k(const float* __restrict__ A,
                                                 const float* __restrict__ Bm,
                                                 float* __restrict__ C, int K, int M,
                                                 const int* __restrict__ tok) {
  __shared__ float As[8][132];
  __shared__ float Bs[8][132];
  const int tid = threadIdx.x;
  const int tx = tid & 15, ty = tid >> 4;
  const int rowBase = blockIdx.y * 128;
  const int colBase = blockIdx.x * 128;
  float acc[8][8];
#pragma unroll
  for (int i = 0; i < 8; i++)
#pragma unroll
    for (int j = 0; j < 8; j++) acc[i][j] = 0.0f;

  for (int k0 = 0; k0 < K; k0 += 8) {
#pragma unroll
    for (int i = 0; i < 4; i++) {
      int lin = tid + i * 256;          // 0..1023
      int r = lin >> 3, kk = lin & 7;
      int gk = k0 + kk;
      float v = 0.0f;
      if (gk < K) {
        int row = rowBase + r; // always < 2048
        size_t arow = EMBED ? (size_t)tok[row] : (size_t)row;
        v = A[arow * K + gk];
      }
      As[kk][r] = v;
    }
#pragma unroll
    for (int i = 0; i < 4; i++) {
      int lin = tid + i * 256;
      int kk = lin >> 7, c = lin & 127;
      int gk = k0 + kk, gc = colBase + c;
      Bs[kk][c] = (gk < K && gc < M) ? Bm[(size_t)gk * M + gc] : 0.0f;
    }
    __syncthreads();
#pragma unroll
    for (int kk = 0; kk < 8; kk++) {
      float av[8], bv[8];
#pragma unroll
      for (int i = 0; i < 8; i++) av[i] = As[kk][ty * 8 + i];
#pragma unroll
      for (int j = 0; j < 8; j++) bv[j] = Bs[kk][tx * 8 + j];
#pragma unroll
      for (int i = 0; i < 8; i++)
#pragma unroll
        for (int j = 0; j < 8; j++) acc[i][j] += av[i] * bv[j];
    }
    __syncthreads();
  }
#pragma unroll
  for (int i = 0; i < 8; i++) {
    int r = rowBase + ty * 8 + i;
#pragma unroll
    for (int j = 0; j < 8; j++) {
      int c = colBase + tx * 8 + j;
      if (c < M) {
        size_t idx = (size_t)r * M + c;
        if (ACCUM)
          C[idx] += acc[i][j];
        else
          C[idx] = acc[i][j];
      }
    }
  }
}

// ---------------- RMS norm over D=1024: one block per row -------------------
__global__ __launch_bounds__(256) void rms_k(const float* __restrict__ x,
                                             const float* __restrict__ w,
                                             float* __restrict__ out) {
  int n = blockIdx.x;
  const float* row = x + (size_t)n * kD;
  float v[4];
  float ss = 0.0f;
#pragma unroll
  for (int i = 0; i < 4; i++) {
    v[i] = row[threadIdx.x + i * 256];
    ss += v[i] * v[i];
  }
#pragma unroll
  for (int off = 32; off > 0; off >>= 1) ss += __shfl_down(ss, off);
  __shared__ float red[4];
  if ((threadIdx.x & 63) == 0) red[threadIdx.x >> 6] = ss;
  __syncthreads();
  float tot = red[0] + red[1] + red[2] + red[3];
  float scale = rsqrtf(tot * (1.0f / kD) + kEPS);
  float* orow = out + (size_t)n * kD;
#pragma unroll
  for (int i = 0; i < 4; i++) {
    int d = threadIdx.x + i * 256;
    orow[d] = v[i] * scale * w[d];
  }
}

// ---------------- per-head RMS (over 64) + RoPE, in place -------------------
// rows = numRows, each row 64 wide; token position = (row / nh) % kT
__global__ __launch_bounds__(256) void qk_norm_rope_k(float* __restrict__ qk,
                                                      const float* __restrict__ nw,
                                                      const float* __restrict__ cost,
                                                      const float* __restrict__ sint,
                                                      int nh) {
  int row = blockIdx.x * 16 + (threadIdx.x >> 4);
  int lane = threadIdx.x & 15;
  float* r = qk + (size_t)row * 64;
  float v[4];
  float ss = 0.0f;
#pragma unroll
  for (int i = 0; i < 4; i++) {
    v[i] = r[lane * 4 + i];
    ss += v[i] * v[i];
  }
#pragma unroll
  for (int m = 1; m < 16; m <<= 1) ss += __shfl_xor(ss, m);
  float scale = rsqrtf(ss * (1.0f / 64.0f) + kEPS);
  float nv[4];
#pragma unroll
  for (int i = 0; i < 4; i++) nv[i] = v[i] * scale * nw[lane * 4 + i];
  int tpos = (row / nh) & (kT - 1);
  float c0 = cost[tpos * 32 + lane * 2 + 0], s0 = sint[tpos * 32 + lane * 2 + 0];
  float c1 = cost[tpos * 32 + lane * 2 + 1], s1 = sint[tpos * 32 + lane * 2 + 1];
  r[lane * 4 + 0] = nv[0] * c0 - nv[1] * s0;
  r[lane * 4 + 1] = nv[0] * s0 + nv[1] * c0;
  r[lane * 4 + 2] = nv[2] * c1 - nv[3] * s1;
  r[lane * 4 + 3] = nv[2] * s1 + nv[3] * c1;
}

// ---------------- flash attention (causal, tanh-capped, MQA) ----------------
// grid (T/64, H, B), 64 threads; thread owns one q row.
__global__ __launch_bounds__(64) void attn_flash_k(const float* __restrict__ q,
                                                   const float* __restrict__ k,
                                                   const float* __restrict__ v,
                                                   float* __restrict__ out) {
  const int b = blockIdx.z, h = blockIdx.y, qb = blockIdx.x;
  const int tid = threadIdx.x;
  const int t = qb * 64 + tid;
  const float* qrow = q + (((size_t)(b * kT + t)) * kH + h) * kHD;
  float qreg[64];
#pragma unroll
  for (int d = 0; d < 64; d++) qreg[d] = qrow[d] * 0.125f; // fold 1/sqrt(64)
  float O[64];
#pragma unroll
  for (int d = 0; d < 64; d++) O[d] = 0.0f;
  float m = -INFINITY, l = 0.0f;
  __shared__ float ks[32][64];
  __shared__ float vs[32][64];
  const int smax = qb * 64 + 63;
  for (int s0 = 0; s0 <= smax; s0 += 32) {
#pragma unroll 4
    for (int r = 0; r < 32; r++) {
      ks[r][tid] = k[((size_t)(b * kT + s0 + r)) * 64 + tid];
      vs[r][tid] = v[((size_t)(b * kT + s0 + r)) * 64 + tid];
    }
    __syncthreads();
    int jend = t - s0 + 1;
    if (jend > 32) jend = 32;
    for (int j = 0; j < jend; j++) {
      float dot = 0.0f;
#pragma unroll
      for (int d = 0; d < 64; d++) dot += qreg[d] * ks[j][d];
      float sc = kCAP * tanhf(dot * (1.0f / kCAP)); // mask==0 for valid s
      float mn = fmaxf(m, sc);
      float corr = __expf(m - mn); // m=-inf first iter -> 0
      float p = __expf(sc - mn);
      l = l * corr + p;
#pragma unroll
      for (int d = 0; d < 64; d++) O[d] = O[d] * corr + p * vs[j][d];
      m = mn;
    }
    __syncthreads();
  }
  float invl = 1.0f / l;
  float* orow = out + ((size_t)(b * kT + t)) * (kH * kHD) + h * kHD;
#pragma unroll
  for (int d = 0; d < 64; d++) orow[d] = O[d] * invl;
}

// ---------------- router: wave per token, fp32 dot, argmax ------------------
__global__ __launch_bounds__(256) void router_k(const float* __restrict__ xn,
                                                const float* __restrict__ rw,
                                                const float* __restrict__ rb,
                                                int* __restrict__ eidx) {
  int n = blockIdx.x * 4 + (threadIdx.x >> 6);
  int lane = threadIdx.x & 63;
  const float* row = xn + (size_t)n * kD;
  float l0 = 0.0f, l1 = 0.0f;
  for (int kk = lane; kk < kD; kk += 64) {
    float xv = row[kk];
    l0 += xv * rw[kk * 2 + 0];
    l1 += xv * rw[kk * 2 + 1];
  }
#pragma unroll
  for (int off = 32; off > 0; off >>= 1) {
    l0 += __shfl_down(l0, off);
    l1 += __shfl_down(l1, off);
  }
  if (lane == 0) eidx[n] = (l1 + rb[1] > l0 + rb[0]) ? 1 : 0;
}

// ---------------- elementwise helpers ---------------------------------------
__global__ __launch_bounds__(256) void silu_mul_k(const float* __restrict__ g,
                                                  const float* __restrict__ u,
                                                  float* __restrict__ out, int n) {
  int i = blockIdx.x * 256 + threadIdx.x;
  if (i < n) {
    float gv = g[i];
    float s = gv / (1.0f + __expf(-gv));
    out[i] = s * u[i];
  }
}

__global__ __launch_bounds__(256) void add_loop_emb_k(const float* __restrict__ h,
                                                      float* __restrict__ x, int t) {
  int idx = blockIdx.x * 256 + threadIdx.x; // kN*kD
  int d = idx & (kD - 1);
  float add = 0.0f;
  if (d < 256) {
    float f = __powf(10000.0f, -(float)d / 256.0f);
    add = sinf((float)t * f);
  } else if (d < 512) {
    float f = __powf(10000.0f, -(float)(d - 256) / 256.0f);
    add = cosf((float)t * f);
  }
  x[idx] = h[idx] + add;
}

__global__ __launch_bounds__(256) void moe_combine_k(float* __restrict__ x,
                                                     const float* __restrict__ y0,
                                                     const float* __restrict__ y1,
                                                     const float* __restrict__ ys,
                                                     const int* __restrict__ eidx) {
  int idx = blockIdx.x * 256 + threadIdx.x; // kN*kD
  int n = idx >> 10;
  const float* y = eidx[n] ? y1 : y0;
  x[idx] += y[idx] + ys[idx];
}

__global__ __launch_bounds__(256) void h_update_k(float* __restrict__ h,
                                                  const float* __restrict__ e,
                                                  const float* __restrict__ x,
                                                  const float* __restrict__ logA,
                                                  const float* __restrict__ logdt,
                                                  const float* __restrict__ Bv,
                                                  const float* __restrict__ gate, int t) {
  int idx = blockIdx.x * 256 + threadIdx.x;
  int d = idx & (kD - 1);
  float z = logdt[0] + logA[d];
  z = fminf(fmaxf(z, -20.0f), 20.0f);
  float A = __expf(-__expf(z));
  float gv = gate[t];
  float g = 1.0f / (1.0f + __expf(-gv));
  h[idx] = A * h[idx] + Bv[d] * e[idx] + g * x[idx];
}

} // namespace

// ---------------------------------------------------------------------------
extern "C" void kernel_launch(void* const* d_in, const int* in_sizes, int n_in,
                              void* d_out, int out_size, void* d_ws, size_t ws_size,
                              hipStream_t stream) {
  const int* tok = (const int*)d_in[0];
  const float* embed_table = (const float*)d_in[1];
  const float* embed_proj = (const float*)d_in[2];
  const float* pre_an = (const float*)d_in[3];
  const float* pre_fn = (const float*)d_in[4];
  const float* pre_wq = (const float*)d_in[5];
  const float* pre_wk = (const float*)d_in[6];
  const float* pre_wv = (const float*)d_in[7];
  const float* pre_wo = (const float*)d_in[8];
  const float* pre_qn = (const float*)d_in[9];
  const float* pre_kn = (const float*)d_in[10];
  const float* pre_g = (const float*)d_in[11];
  const float* pre_u = (const float*)d_in[12];
  const float* pre_d = (const float*)d_in[13];
  const float* rec_an = (const float*)d_in[14];
  const float* rec_fn = (const float*)d_in[15];
  const float* rec_wq = (const float*)d_in[16];
  const float* rec_wk = (const float*)d_in[17];
  const float* rec_wv = (const float*)d_in[18];
  const float* rec_wo = (const float*)d_in[19];
  const float* rec_qn = (const float*)d_in[20];
  const float* rec_kn = (const float*)d_in[21];
  const float* rec_router = (const float*)d_in[22];
  const float* rec_rbias = (const float*)d_in[23];
  const float* rec_eg = (const float*)d_in[24];
  const float* rec_eu = (const float*)d_in[25];
  const float* rec_ed = (const float*)d_in[26];
  const float* rec_sg = (const float*)d_in[27];
  const float* rec_su = (const float*)d_in[28];
  const float* rec_sd = (const float*)d_in[29];
  const float* lti_logA = (const float*)d_in[30];
  const float* lti_logdt = (const float*)d_in[31];
  const float* lti_B = (const float*)d_in[32];
  const float* gate_emb = (const float*)d_in[33];
  const float* coda_an = (const float*)d_in[34];
  const float* coda_fn = (const float*)d_in[35];
  const float* coda_wq = (const float*)d_in[36];
  const float* coda_wk = (const float*)d_in[37];
  const float* coda_wv = (const float*)d_in[38];
  const float* coda_wo = (const float*)d_in[39];
  const float* coda_qn = (const float*)d_in[40];
  const float* coda_kn = (const float*)d_in[41];
  const float* coda_g = (const float*)d_in[42];
  const float* coda_u = (const float*)d_in[43];
  const float* coda_d = (const float*)d_in[44];
  const float* final_norm = (const float*)d_in[45];
  const float* lm_head = (const float*)d_in[46];
  float* out = (float*)d_out;

  // ---- workspace layout (floats) ----
  float* ws = (float*)d_ws;
  const size_t ND = (size_t)kN * kD;           // 2097152
  const size_t NDFF = (size_t)kN * kDFF;       // 2795520
  float* e_buf = ws;                            // ND
  float* h_buf = e_buf + ND;                    // ND
  float* x_buf = h_buf + ND;                    // ND
  float* xn_buf = x_buf + ND;                   // ND
  float* q_buf = xn_buf + ND;                   // ND   (reused as ybuf0)
  float* a_buf = q_buf + ND;                    // ND   (reused as ybuf1)
  float* ys_buf = a_buf + ND;                   // ND
  float* g_buf = ys_buf + ND;                   // NDFF
  float* u_buf = g_buf + NDFF;                  // NDFF
  float* k_buf = u_buf + NDFF;                  // kN*64
  float* v_buf = k_buf + (size_t)kN * 64;       // kN*64
  float* cost = v_buf + (size_t)kN * 64;        // kT*32
  float* sint = cost + (size_t)kT * 32;         // kT*32
  int* eidx = (int*)(sint + (size_t)kT * 32);   // kN ints

  const dim3 blk256(256);
  const dim3 g_D(kD / 128, kN / 128);           // (8,16) for M=1024
  const dim3 g_64(1, kN / 128);                 // M=64
  const dim3 g_DFF((kDFF + 127) / 128, kN / 128); // (11,16)
  const dim3 g_V((kV + 127) / 128, kN / 128);   // (393,16)
  const int ew_blocks = (int)(ND / 256);        // 8192

  // tables + embedding
  rope_tables_k<<<kT * 32 / 256, blk256, 0, stream>>>(cost, sint);
  gemm128_k<false, true><<<dim3(kD / 128, kN / 128), blk256, 0, stream>>>(
      embed_table, embed_proj, e_buf, kE, kD, tok);
  hipMemcpyAsync(h_buf, e_buf, ND * sizeof(float), hipMemcpyDeviceToDevice, stream);

  auto attn_block = [&](const float* an, const float* wq, const float* wk,
                        const float* wv, const float* wo, const float* qn,
                        const float* kn, float* target) {
    rms_k<<<kN, blk256, 0, stream>>>(target, an, xn_buf);
    gemm128_k<false, false><<<g_D, blk256, 0, stream>>>(xn_buf, wq, q_buf, kD, kH * kHD, nullptr);
    gemm128_k<false, false><<<g_64, blk256, 0, stream>>>(xn_buf, wk, k_buf, kD, kHD, nullptr);
    gemm128_k<false, false><<<g_64, blk256, 0, stream>>>(xn_buf, wv, v_buf, kD, kHD, nullptr);
    qk_norm_rope_k<<<kN * kH / 16, blk256, 0, stream>>>(q_buf, qn, cost, sint, kH);
    qk_norm_rope_k<<<kN / 16, blk256, 0, stream>>>(k_buf, kn, cost, sint, 1);
    attn_flash_k<<<dim3(kT / 64, kH, kB), dim3(64), 0, stream>>>(q_buf, k_buf, v_buf, a_buf);
    gemm128_k<true, false><<<g_D, blk256, 0, stream>>>(a_buf, wo, target, kH * kHD, kD, nullptr);
  };

  auto swiglu_block = [&](const float* fn, const float* wg, const float* wu,
                          const float* wd, float* target) {
    rms_k<<<kN, blk256, 0, stream>>>(target, fn, xn_buf);
    gemm128_k<false, false><<<g_DFF, blk256, 0, stream>>>(xn_buf, wg, g_buf, kD, kDFF, nullptr);
    gemm128_k<false, false><<<g_DFF, blk256, 0, stream>>>(xn_buf, wu, u_buf, kD, kDFF, nullptr);
    silu_mul_k<<<(int)((NDFF + 255) / 256), blk256, 0, stream>>>(g_buf, u_buf, g_buf, (int)NDFF);
    gemm128_k<true, false><<<g_D, blk256, 0, stream>>>(g_buf, wd, target, kDFF, kD, nullptr);
  };

  // ---- pre block ----
  attn_block(pre_an, pre_wq, pre_wk, pre_wv, pre_wo, pre_qn, pre_kn, h_buf);
  swiglu_block(pre_fn, pre_g, pre_u, pre_d, h_buf);

  // ---- recurrent loop ----
  for (int t = 0; t < kL; t++) {
    add_loop_emb_k<<<ew_blocks, blk256, 0, stream>>>(h_buf, x_buf, t);
    attn_block(rec_an, rec_wq, rec_wk, rec_wv, rec_wo, rec_qn, rec_kn, x_buf);

    // MoE
    rms_k<<<kN, blk256, 0, stream>>>(x_buf, rec_fn, xn_buf);
    router_k<<<kN / 4, blk256, 0, stream>>>(xn_buf, rec_router, rec_rbias, eidx);
    float* ybuf[2] = {q_buf, a_buf}; // q/a free during MoE phase
    for (int ex = 0; ex < 2; ex++) {
      const float* eg = rec_eg + (size_t)ex * kD * kEXP;
      const float* eu = rec_eu + (size_t)ex * kD * kEXP;
      const float* ed = rec_ed + (size_t)ex * kEXP * kD;
      gemm128_k<false, false><<<g_D, blk256, 0, stream>>>(xn_buf, eg, g_buf, kD, kEXP, nullptr);
      gemm128_k<false, false><<<g_D, blk256, 0, stream>>>(xn_buf, eu, u_buf, kD, kEXP, nullptr);
      silu_mul_k<<<ew_blocks, blk256, 0, stream>>>(g_buf, u_buf, g_buf, (int)ND);
      gemm128_k<false, false><<<g_D, blk256, 0, stream>>>(g_buf, ed, ybuf[ex], kEXP, kD, nullptr);
    }
    gemm128_k<false, false><<<g_D, blk256, 0, stream>>>(xn_buf, rec_sg, g_buf, kD, kEXP, nullptr);
    gemm128_k<false, false><<<g_D, blk256, 0, stream>>>(xn_buf, rec_su, u_buf, kD, kEXP, nullptr);
    silu_mul_k<<<ew_blocks, blk256, 0, stream>>>(g_buf, u_buf, g_buf, (int)ND);
    gemm128_k<false, false><<<g_D, blk256, 0, stream>>>(g_buf, rec_sd, ys_buf, kEXP, kD, nullptr);
    moe_combine_k<<<ew_blocks, blk256, 0, stream>>>(x_buf, ybuf[0], ybuf[1], ys_buf, eidx);

    h_update_k<<<ew_blocks, blk256, 0, stream>>>(h_buf, e_buf, x_buf, lti_logA, lti_logdt,
                                                 lti_B, gate_emb, t);
  }

  // ---- coda block ----
  attn_block(coda_an, coda_wq, coda_wk, coda_wv, coda_wo, coda_qn, coda_kn, h_buf);
  swiglu_block(coda_fn, coda_g, coda_u, coda_d, h_buf);

  // ---- lm head ----
  rms_k<<<kN, blk256, 0, stream>>>(h_buf, final_norm, xn_buf);
  gemm128_k<false, false><<<g_V, blk256, 0, stream>>>(xn_buf, lm_head, out, kD, kV, nullptr);
}